// Round 11
// baseline (179.910 us; speedup 1.0000x reference)
//
#include <hip/hip_runtime.h>

#define NB 16
#define NC 256
#define NH 56
#define NW 56
#define NHW (NH * NW)          // 3136
#define NK 256
#define TK_THREADS 1024
#define CAP 1024

// pass1 geometry: 4-row band x half the channels per block -> 448 blocks
#define BR 4                   // compute rows per band
#define RS 6                   // staged rows (4 compute + 2 halo)
#define CS 16                  // channels per staged chunk
#define CHALF 128              // channels per block
#define NCHUNK_H (CHALF / CS)  // 8 chunks per block
#define CHUNK16 (CS * RS * NW / 4)        // 1344 16B-chunks per stage
#define NBAND (NH / BR)                   // 14
#define P1_BLOCKS (NB * NBAND * 2)        // 448 (56 per XCD)
#define NQ (BR * (NW / 4))                // 56 quads per band
#define MAPS (NB * NHW)                   // elements per map

// ---- sortable-float helpers -------------------------------------------------
__device__ inline unsigned int flip_f32(float f) {
    unsigned int u = __float_as_uint(f);
    return (u & 0x80000000u) ? ~u : (u | 0x80000000u);
}
__device__ inline float unflip_f32(unsigned int u) {
    u = (u & 0x80000000u) ? (u ^ 0x80000000u) : ~u;
    return __uint_as_float(u);
}

// ---- kernel 1: partial norm2 / hprod / vprod maps (R10-exact) ---------------
__global__ void __launch_bounds__(256)
pass1_kernel(const float* __restrict__ f, float* __restrict__ maps) {
    __shared__ __align__(16) float buf[2][CS * RS * NW];   // 2 x 21504 B
    __shared__ float redbuf[NQ][4][12];                    // 10752 B

    int bid = blockIdx.x;
    int sb = (bid & 7) * (P1_BLOCKS / 8) + (bid >> 3);   // XCD-chunked
    int b = sb / 28;
    int rem0 = sb - b * 28;
    int band = rem0 >> 1;
    int chh = rem0 & 1;            // channel half
    int y0 = band * BR;
    int tid = threadIdx.x;
    const float* fb = f + (size_t)b * NC * NHW + (size_t)chh * CHALF * NHW;

    auto stage = [&](int ci, float* dst) {
        int c0 = ci * CS;
#pragma unroll
        for (int i = 0; i < 6; ++i) {
            int k = tid + 256 * i;
            if (k < CHUNK16) {
                int ch = k / (RS * 14);            // 84 16B-chunks per channel
                int rem = k - ch * (RS * 14);
                int rl = rem / 14;                 // staged row 0..5
                int xk = rem - rl * 14;            // 16B chunk within row
                int rg = y0 - 1 + rl;
                rg = rg < 0 ? 0 : (rg > NH - 1 ? NH - 1 : rg);
                const float* src = fb + (size_t)(c0 + ch) * NHW + rg * NW + xk * 4;
                __builtin_amdgcn_global_load_lds(
                    (const __attribute__((address_space(1))) void*)src,
                    (__attribute__((address_space(3))) void*)(dst + k * 4),
                    16, 0, 0);
            }
        }
    };

    // compute geometry: tid<224 -> quad (4 rows x 14 quads) x chgroup(4)
    int chg = tid / NQ;                 // 0..3, each handles 4 ch per chunk
    int quad = tid - chg * NQ;          // 0..55
    int r = quad / 14, qx = quad - r * 14, x0 = qx * 4;
    int xl = x0 ? x0 - 1 : 0;
    int xr = (x0 + 4 < NW) ? x0 + 4 : NW - 1;

    float n0 = 0.f, n1 = 0.f, n2 = 0.f, n3 = 0.f;
    float h0 = 0.f, h1 = 0.f, h2 = 0.f, h3 = 0.f;
    float w0 = 0.f, w1 = 0.f, w2 = 0.f, w3 = 0.f;

    stage(0, buf[0]);
    __syncthreads();                            // drains staging
    for (int ci = 0; ci < NCHUNK_H; ++ci) {
        if (ci + 1 < NCHUNK_H) stage(ci + 1, buf[(ci + 1) & 1]);
        if (tid < 4 * NQ) {
            const float* sbf = buf[ci & 1];
#pragma unroll
            for (int c = 0; c < 4; ++c) {
                const float* Bm = sbf + (chg * 4 + c) * (RS * NW) + (r + 1) * NW;
                float4 v = *(const float4*)(Bm + x0);
                float  l = Bm[xl];
                float  rr = Bm[xr];
                float4 u = *(const float4*)(Bm + NW + x0);   // global y+1
                float4 d = *(const float4*)(Bm - NW + x0);   // global y-1
                n0 += v.x * v.x; n1 += v.y * v.y; n2 += v.z * v.z; n3 += v.w * v.w;
                h0 += l * v.y;   h1 += v.x * v.z; h2 += v.y * v.w; h3 += v.z * rr;
                w0 += u.x * d.x; w1 += u.y * d.y; w2 += u.z * d.z; w3 += u.w * d.w;
            }
        }
        __syncthreads();   // compute done + next stage landed
    }

    if (tid < 4 * NQ) {
        float* rb = redbuf[quad][chg];
        rb[0] = n0; rb[1] = n1; rb[2]  = n2; rb[3]  = n3;
        rb[4] = h0; rb[5] = h1; rb[6]  = h2; rb[7]  = h3;
        rb[8] = w0; rb[9] = w1; rb[10] = w2; rb[11] = w3;
    }
    __syncthreads();

    // maps layout: [chh][comp-class][B*HW]: n,h,v for half0 then half1
    float* mbase = maps + (size_t)chh * 3 * MAPS;
    for (int oi = tid; oi < NQ * 12; oi += 256) {
        int q = oi / 12, comp = oi - q * 12;
        float acc = 0.f;
#pragma unroll
        for (int g = 0; g < 4; ++g) acc += redbuf[q][g][comp];
        int r2 = q / 14, qx2 = q - r2 * 14;
        int j = comp & 3;
        float* m = mbase + (size_t)(comp >> 2) * MAPS;   // 0:n 1:h 2:v
        m[((size_t)b * NH + y0 + r2) * NW + qx2 * 4 + j] = acc;
    }
}

// ---- kernel 2: sim-finish (R10-exact) ---------------------------------------
__global__ void __launch_bounds__(256)
sim_kernel(const float* __restrict__ maps, unsigned int* __restrict__ sv) {
    int pix = blockIdx.x * 256 + threadIdx.x;
    if (pix >= NB * NHW) return;
    int b = pix / NHW, i = pix - b * NHW;
    const float* na  = maps + (size_t)b * NHW;
    const float* ha  = na + MAPS;
    const float* va  = na + 2 * (size_t)MAPS;
    const float* nb2 = na + 3 * (size_t)MAPS;
    const float* hb2 = na + 4 * (size_t)MAPS;
    const float* vb2 = na + 5 * (size_t)MAPS;

    int y = i / NW, x = i - y * NW;
    int xl = (x > 0) ? x - 1 : 0;
    int xr = (x < NW - 1) ? x + 1 : NW - 1;
    int yu = (y < NH - 1) ? y + 1 : NH - 1;
    int yd = (y > 0) ? y - 1 : 0;
    int il = y * NW + xl, ir = y * NW + xr;
    int iu = yu * NW + x, id = yd * NW + x;

    float nl = na[il] + nb2[il];
    float nr = na[ir] + nb2[ir];
    float nu = na[iu] + nb2[iu];
    float nd = na[id] + nb2[id];
    float h = ha[i] + hb2[i], v = va[i] + vb2[i];
    float s = 0.5f * (h / (sqrtf(nl) * sqrtf(nr)) + v / (sqrtf(nu) * sqrtf(nd)));
    sv[pix] = flip_f32(s);
}

// ---- kernel 3: per-batch top-K (R10 algorithm, looped x12 for MEASUREMENT) --
__global__ void __launch_bounds__(TK_THREADS)
topk_kernel(const unsigned int* __restrict__ sv, int* __restrict__ idx_out,
            float* __restrict__ vals_out, float* __restrict__ y_out,
            float* __restrict__ x_out) {
    __shared__ unsigned int svals[NHW];          // flipped sim values
    __shared__ unsigned int hist16[16][256];     // per-wave histograms
    __shared__ unsigned long long cand[CAP];
    __shared__ unsigned int sh_prefix, sh_mask;
    __shared__ int sh_cnt, sh_above, sh_setS, sh_done;

    const int b = blockIdx.x;
    const int tid = threadIdx.x;
    const int lane = tid & 63;
    const int wv = tid >> 6;
    const unsigned int* svb = sv + (size_t)b * NHW;

    for (int rep = 0; rep < 12; ++rep) {
        __syncthreads();   // previous rep fully done

        for (int i = tid; i < NHW; i += TK_THREADS) svals[i] = svb[i];
        if (tid == 0) { sh_prefix = 0u; sh_mask = 0u; sh_above = 0; sh_done = 0; }

        int shift = 24;
        for (int stage = 0; stage < 4; ++stage) {
            __syncthreads();
            if (sh_done) break;
            for (int i = tid; i < 16 * 256; i += TK_THREADS) ((unsigned int*)hist16)[i] = 0u;
            __syncthreads();
            unsigned int pfx = sh_prefix, msk = sh_mask;
            for (int i = tid; i < NHW; i += TK_THREADS) {
                unsigned int v = svals[i];
                if ((v & msk) == pfx) atomicAdd(&hist16[wv][(v >> shift) & 255u], 1u);
            }
            __syncthreads();
            if (tid < 64) {                 // wave 0: parallel suffix-scan + pick
                int l = tid;
                unsigned int kneed = (unsigned int)(NK - sh_above);
                unsigned int h0 = 0, h1 = 0, h2 = 0, h3 = 0;
#pragma unroll
                for (int w = 0; w < 16; ++w) {
                    h0 += hist16[w][4 * l + 0]; h1 += hist16[w][4 * l + 1];
                    h2 += hist16[w][4 * l + 2]; h3 += hist16[w][4 * l + 3];
                }
                unsigned int lsum = h0 + h1 + h2 + h3;
                unsigned int s = lsum;
#pragma unroll
                for (int d = 1; d < 64; d <<= 1) {
                    unsigned int t = __shfl_down(s, d);
                    s += (l + d < 64) ? t : 0u;
                }
                unsigned int above_l = s - lsum;      // digits in lanes > l
                unsigned int suf3 = above_l + h3;
                unsigned int suf2 = suf3 + h2;
                unsigned int suf1 = suf2 + h1;
                unsigned int suf0 = suf1 + h0;
                bool has = (suf0 >= kneed);
                unsigned long long bal = __ballot(has);
                int hl = 63 - __clzll(bal);           // highest lane with a hit
                if (l == hl) {
                    int c; unsigned int above, hc;
                    if (suf3 >= kneed)      { c = 4 * l + 3; above = above_l; hc = h3; }
                    else if (suf2 >= kneed) { c = 4 * l + 2; above = suf3;    hc = h2; }
                    else if (suf1 >= kneed) { c = 4 * l + 1; above = suf2;    hc = h1; }
                    else                    { c = 4 * l + 0; above = suf1;    hc = h0; }
                    sh_above += (int)above;
                    sh_setS = (int)hc;
                    sh_prefix |= ((unsigned int)c) << shift;
                    sh_mask   |= 255u << shift;
                    if (sh_above + sh_setS <= 512 || shift == 0) sh_done = 1;
                }
            }
            shift -= 8;
        }
        __syncthreads();

        // ballot-aggregated compaction of candidates v >= T
        if (tid == 0) sh_cnt = 0;
        __syncthreads();
        unsigned int T = sh_prefix;
        for (int i = tid; i < NHW; i += TK_THREADS) {
            unsigned int v = svals[i];
            bool keep = (v >= T);
            unsigned long long m = __ballot(keep);
            int basep = 0;
            if (lane == 0) basep = atomicAdd(&sh_cnt, __popcll(m));
            basep = __shfl(basep, 0);
            if (keep) {
                int pos = basep + __popcll(m & ((1ull << lane) - 1ull));
                if (pos < CAP)
                    cand[pos] = ((unsigned long long)v << 32) |
                                (unsigned long long)(0xFFFFFFFFu - (unsigned int)i);
            }
        }
        __syncthreads();
        int nc = sh_cnt; if (nc > CAP) nc = CAP;
        const int NS = (nc <= 512) ? 512 : CAP;
        for (int i = tid; i < NS; i += TK_THREADS) if (i >= nc) cand[i] = 0ull;
        __syncthreads();

        // bitonic sort NS keys descending
        for (int k = 2; k <= NS; k <<= 1) {
            for (int j = k >> 1; j > 0; j >>= 1) {
                for (int i = tid; i < NS; i += TK_THREADS) {
                    int ixj = i ^ j;
                    if (ixj > i) {
                        unsigned long long a = cand[i], c2 = cand[ixj];
                        bool sw = ((i & k) == 0) ? (a < c2) : (a > c2);
                        if (sw) { cand[i] = c2; cand[ixj] = a; }
                    }
                }
                __syncthreads();
            }
        }

        if (tid < NK) {
            unsigned long long kk = cand[tid];
            unsigned int lo = (unsigned int)(kk & 0xFFFFFFFFull);
            int idx = (int)(0xFFFFFFFFu - lo);
            float val = unflip_f32((unsigned int)(kk >> 32));
            int o = b * NK + tid;
            idx_out[o] = idx;
            vals_out[o] = val;
            y_out[o] = (float)(idx / NW);
            x_out[o] = (float)(idx % NW);
        }
    }
}

// ---- kernel 4: gather (R10 algorithm, looped x8 for MEASUREMENT) ------------
__global__ void __launch_bounds__(256)
gather_kernel(const float* __restrict__ f, const int* __restrict__ idx,
              float* __restrict__ out) {
    int bid = blockIdx.x;              // 1024
    int xcd = bid & 7, i = bid >> 3;   // i 0..127
    int b = xcd + 8 * (i & 1);
    int kg = i >> 1;                   // 0..63
    int c = threadIdx.x;
    const float* fb = f + (size_t)b * NC * NHW + (size_t)c * NHW;
    for (int rep = 0; rep < 8; ++rep) {
#pragma unroll
        for (int j = 0; j < 4; ++j) {
            int k = kg * 4 + j;
            int p = idx[b * NK + k];       // uniform -> scalar load
            out[((size_t)b * NK + k) * NC + c] = fb[p];
        }
        __asm__ __volatile__("" ::: "memory");   // keep reps distinct (no CSE/DCE)
    }
}

extern "C" void kernel_launch(void* const* d_in, const int* in_sizes, int n_in,
                              void* d_out, int out_size, void* d_ws, size_t ws_size,
                              hipStream_t stream) {
    const float* f = (const float*)d_in[0];

    // output layout: point_feat [B,K,C] | vals [B,K] | ycoord [B,K] | xcoord [B,K]
    float* out_feat = (float*)d_out;
    float* out_vals = out_feat + (size_t)NB * NK * NC;
    float* out_y    = out_vals + (size_t)NB * NK;
    float* out_x    = out_y    + (size_t)NB * NK;

    // workspace: 6 partial maps | svals map | idx
    float* maps = (float*)d_ws;
    unsigned int* sv = (unsigned int*)(maps + 6 * (size_t)MAPS);
    int* idx = (int*)(sv + MAPS);

    pass1_kernel<<<P1_BLOCKS, 256, 0, stream>>>(f, maps);
    sim_kernel<<<(NB * NHW + 255) / 256, 256, 0, stream>>>(maps, sv);
    topk_kernel<<<NB, TK_THREADS, 0, stream>>>(sv, idx, out_vals, out_y, out_x);
    gather_kernel<<<NB * NK / 4, 256, 0, stream>>>(f, idx, out_feat);
}

// Round 12
// 37.970 us; speedup vs baseline: 4.7382x; 4.7382x over previous
//
#include <hip/hip_runtime.h>

#define NB 16
#define NC 256
#define NH 56
#define NW 56
#define NHW (NH * NW)          // 3136
#define NK 256
#define CAP 1024

// pass1 geometry: 4-row band x half the channels per block -> 448 blocks
#define BR 4                   // compute rows per band
#define RS 6                   // staged rows (4 compute + 2 halo)
#define CS 16                  // channels per staged chunk
#define CHALF 128              // channels per block
#define NCHUNK_H (CHALF / CS)  // 8 chunks per block
#define CHUNK16 (CS * RS * NW / 4)        // 1344 16B-chunks per stage
#define NBAND (NH / BR)                   // 14
#define P1_BLOCKS (NB * NBAND * 2)        // 448 (56 per XCD)
#define NQ (BR * (NW / 4))                // 56 quads per band
#define MAPS (NB * NHW)                   // elements per map

// ---- sortable-float helpers -------------------------------------------------
__device__ inline unsigned int flip_f32(float f) {
    unsigned int u = __float_as_uint(f);
    return (u & 0x80000000u) ? ~u : (u | 0x80000000u);
}
__device__ inline float unflip_f32(unsigned int u) {
    u = (u & 0x80000000u) ? (u ^ 0x80000000u) : ~u;
    return __uint_as_float(u);
}

// ---- kernel 1: partial norm2 / hprod / vprod maps (R10-exact) ---------------
__global__ void __launch_bounds__(256)
pass1_kernel(const float* __restrict__ f, float* __restrict__ maps) {
    __shared__ __align__(16) float buf[2][CS * RS * NW];   // 2 x 21504 B
    __shared__ float redbuf[NQ][4][12];                    // 10752 B

    int bid = blockIdx.x;
    int sb = (bid & 7) * (P1_BLOCKS / 8) + (bid >> 3);   // XCD-chunked
    int b = sb / 28;
    int rem0 = sb - b * 28;
    int band = rem0 >> 1;
    int chh = rem0 & 1;            // channel half
    int y0 = band * BR;
    int tid = threadIdx.x;
    const float* fb = f + (size_t)b * NC * NHW + (size_t)chh * CHALF * NHW;

    auto stage = [&](int ci, float* dst) {
        int c0 = ci * CS;
#pragma unroll
        for (int i = 0; i < 6; ++i) {
            int k = tid + 256 * i;
            if (k < CHUNK16) {
                int ch = k / (RS * 14);            // 84 16B-chunks per channel
                int rem = k - ch * (RS * 14);
                int rl = rem / 14;                 // staged row 0..5
                int xk = rem - rl * 14;            // 16B chunk within row
                int rg = y0 - 1 + rl;
                rg = rg < 0 ? 0 : (rg > NH - 1 ? NH - 1 : rg);
                const float* src = fb + (size_t)(c0 + ch) * NHW + rg * NW + xk * 4;
                __builtin_amdgcn_global_load_lds(
                    (const __attribute__((address_space(1))) void*)src,
                    (__attribute__((address_space(3))) void*)(dst + k * 4),
                    16, 0, 0);
            }
        }
    };

    // compute geometry: tid<224 -> quad (4 rows x 14 quads) x chgroup(4)
    int chg = tid / NQ;                 // 0..3, each handles 4 ch per chunk
    int quad = tid - chg * NQ;          // 0..55
    int r = quad / 14, qx = quad - r * 14, x0 = qx * 4;
    int xl = x0 ? x0 - 1 : 0;
    int xr = (x0 + 4 < NW) ? x0 + 4 : NW - 1;

    float n0 = 0.f, n1 = 0.f, n2 = 0.f, n3 = 0.f;
    float h0 = 0.f, h1 = 0.f, h2 = 0.f, h3 = 0.f;
    float w0 = 0.f, w1 = 0.f, w2 = 0.f, w3 = 0.f;

    stage(0, buf[0]);
    __syncthreads();                            // drains staging
    for (int ci = 0; ci < NCHUNK_H; ++ci) {
        if (ci + 1 < NCHUNK_H) stage(ci + 1, buf[(ci + 1) & 1]);
        if (tid < 4 * NQ) {
            const float* sbf = buf[ci & 1];
#pragma unroll
            for (int c = 0; c < 4; ++c) {
                const float* Bm = sbf + (chg * 4 + c) * (RS * NW) + (r + 1) * NW;
                float4 v = *(const float4*)(Bm + x0);
                float  l = Bm[xl];
                float  rr = Bm[xr];
                float4 u = *(const float4*)(Bm + NW + x0);   // global y+1
                float4 d = *(const float4*)(Bm - NW + x0);   // global y-1
                n0 += v.x * v.x; n1 += v.y * v.y; n2 += v.z * v.z; n3 += v.w * v.w;
                h0 += l * v.y;   h1 += v.x * v.z; h2 += v.y * v.w; h3 += v.z * rr;
                w0 += u.x * d.x; w1 += u.y * d.y; w2 += u.z * d.z; w3 += u.w * d.w;
            }
        }
        __syncthreads();   // compute done + next stage landed
    }

    if (tid < 4 * NQ) {
        float* rb = redbuf[quad][chg];
        rb[0] = n0; rb[1] = n1; rb[2]  = n2; rb[3]  = n3;
        rb[4] = h0; rb[5] = h1; rb[6]  = h2; rb[7]  = h3;
        rb[8] = w0; rb[9] = w1; rb[10] = w2; rb[11] = w3;
    }
    __syncthreads();

    // maps layout: [chh][comp-class][B*HW]: n,h,v for half0 then half1
    float* mbase = maps + (size_t)chh * 3 * MAPS;
    for (int oi = tid; oi < NQ * 12; oi += 256) {
        int q = oi / 12, comp = oi - q * 12;
        float acc = 0.f;
#pragma unroll
        for (int g = 0; g < 4; ++g) acc += redbuf[q][g][comp];
        int r2 = q / 14, qx2 = q - r2 * 14;
        int j = comp & 3;
        float* m = mbase + (size_t)(comp >> 2) * MAPS;   // 0:n 1:h 2:v
        m[((size_t)b * NH + y0 + r2) * NW + qx2 * 4 + j] = acc;
    }
}

// ---- kernel 2: sim-finish (R10-exact) ---------------------------------------
__global__ void __launch_bounds__(256)
sim_kernel(const float* __restrict__ maps, unsigned int* __restrict__ sv) {
    int pix = blockIdx.x * 256 + threadIdx.x;
    if (pix >= NB * NHW) return;
    int b = pix / NHW, i = pix - b * NHW;
    const float* na  = maps + (size_t)b * NHW;
    const float* ha  = na + MAPS;
    const float* va  = na + 2 * (size_t)MAPS;
    const float* nb2 = na + 3 * (size_t)MAPS;
    const float* hb2 = na + 4 * (size_t)MAPS;
    const float* vb2 = na + 5 * (size_t)MAPS;

    int y = i / NW, x = i - y * NW;
    int xl = (x > 0) ? x - 1 : 0;
    int xr = (x < NW - 1) ? x + 1 : NW - 1;
    int yu = (y < NH - 1) ? y + 1 : NH - 1;
    int yd = (y > 0) ? y - 1 : 0;
    int il = y * NW + xl, ir = y * NW + xr;
    int iu = yu * NW + x, id = yd * NW + x;

    float nl = na[il] + nb2[il];
    float nr = na[ir] + nb2[ir];
    float nu = na[iu] + nb2[iu];
    float nd = na[id] + nb2[id];
    float h = ha[i] + hb2[i], v = va[i] + vb2[i];
    float s = 0.5f * (h / (sqrtf(nl) * sqrtf(nr)) + v / (sqrtf(nu) * sqrtf(nd)));
    sv[pix] = flip_f32(s);
}

// ---- kernel 3: per-batch top-K — 12-bit radix digest + counting-rank --------
// Stage A: 4096-bin histogram of bits[31:20] -> exact threshold in ONE pass
// for concentrated float data (old 8-bit version needed 3-4 passes).
// Refinement stages (bits[19:8], bits[7:0]) only on heavy ties (same
// guarantees as before). Then counting-rank of <=CAP candidates replaces the
// 45-barrier bitonic sort. key = flip(val)<<32 | ~idx  == jax.lax.top_k order.
__global__ void __launch_bounds__(1024)
topk_kernel(const unsigned int* __restrict__ sv, int* __restrict__ idx_out,
            float* __restrict__ vals_out, float* __restrict__ y_out,
            float* __restrict__ x_out) {
    __shared__ unsigned int svals[NHW];
    __shared__ unsigned int hist[4096];
    __shared__ unsigned int wtot[16];
    __shared__ unsigned long long cand[CAP];
    __shared__ unsigned int sh_prefix, sh_mask;
    __shared__ int sh_above, sh_setS, sh_done, sh_cnt;

    const int b = blockIdx.x;
    const int tid = threadIdx.x;
    const int lane = tid & 63;
    const int wv = tid >> 6;
    const unsigned int* svb = sv + (size_t)b * NHW;

    for (int i = tid; i < NHW; i += 1024) svals[i] = svb[i];
    if (tid == 0) { sh_prefix = 0u; sh_mask = 0u; sh_above = 0; sh_done = 0; }

    const int shifts[3] = {20, 8, 0};
    const unsigned int wmasks[3] = {0xFFFu, 0xFFFu, 0xFFu};
    for (int st = 0; st < 3; ++st) {
        __syncthreads();
        int kneed = NK - sh_above;          // read post-barrier, pre-update
        if (sh_done) break;
        for (int i = tid; i < 4096; i += 1024) hist[i] = 0u;
        __syncthreads();
        unsigned int pfx = sh_prefix, msk = sh_mask;
        int shift = shifts[st];
        unsigned int wmask = wmasks[st];
        for (int i = tid; i < NHW; i += 1024) {
            unsigned int v = svals[i];
            if ((v & msk) == pfx) atomicAdd(&hist[(v >> shift) & wmask], 1u);
        }
        __syncthreads();
        // block-wide suffix scan: thread t owns bins 4t..4t+3 (ascending value)
        unsigned int b0 = hist[4 * tid], b1 = hist[4 * tid + 1];
        unsigned int b2 = hist[4 * tid + 2], b3 = hist[4 * tid + 3];
        unsigned int lsum = b0 + b1 + b2 + b3;
        unsigned int s = lsum;
#pragma unroll
        for (int d = 1; d < 64; d <<= 1) {
            unsigned int t2 = __shfl_down(s, d);
            s += (lane + d < 64) ? t2 : 0u;
        }
        if (lane == 0) wtot[wv] = s;        // wave total
        __syncthreads();
        unsigned int wabove = 0;
        for (int w = wv + 1; w < 16; ++w) wabove += wtot[w];
        unsigned int thr_above = wabove + (s - lsum);   // strictly above my bins
        unsigned int suf3 = thr_above + b3;
        unsigned int suf2 = suf3 + b2;
        unsigned int suf1 = suf2 + b1;
        unsigned int suf0 = suf1 + b0;
        // unique boundary thread self-identifies
        if (suf0 >= (unsigned int)kneed && thr_above < (unsigned int)kneed) {
            int c; unsigned int above, hc;
            if (suf3 >= (unsigned int)kneed)      { c = 4 * tid + 3; above = thr_above; hc = b3; }
            else if (suf2 >= (unsigned int)kneed) { c = 4 * tid + 2; above = suf3;      hc = b2; }
            else if (suf1 >= (unsigned int)kneed) { c = 4 * tid + 1; above = suf2;      hc = b1; }
            else                                  { c = 4 * tid + 0; above = suf1;      hc = b0; }
            sh_above += (int)above;
            sh_setS = (int)hc;
            sh_prefix = pfx | ((unsigned int)c << shift);
            sh_mask = msk | (wmask << shift);
            if (sh_above + sh_setS <= CAP || st == 2) sh_done = 1;
        }
    }
    __syncthreads();

    // ballot-aggregated compaction of candidates v >= T
    if (tid == 0) sh_cnt = 0;
    __syncthreads();
    unsigned int T = sh_prefix;
    for (int i = tid; i < NHW; i += 1024) {
        unsigned int v = svals[i];
        bool keep = (v >= T);
        unsigned long long m = __ballot(keep);
        int basep = 0;
        if (lane == 0) basep = atomicAdd(&sh_cnt, __popcll(m));
        basep = __shfl(basep, 0);
        if (keep) {
            int pos = basep + __popcll(m & ((1ull << lane) - 1ull));
            if (pos < CAP)
                cand[pos] = ((unsigned long long)v << 32) |
                            (unsigned long long)(0xFFFFFFFFu - (unsigned int)i);
        }
    }
    __syncthreads();
    int nc = sh_cnt; if (nc > CAP) nc = CAP;

    // counting-rank: thread t ranks its candidate against all nc (LDS
    // broadcast reads), writes straight to out[rank] — no sort barriers.
    if (tid < nc) {
        unsigned long long my = cand[tid];
        int rank = 0;
        for (int i = 0; i < nc; ++i) rank += (cand[i] > my);
        if (rank < NK) {
            unsigned int lo = (unsigned int)(my & 0xFFFFFFFFull);
            int idx = (int)(0xFFFFFFFFu - lo);
            float val = unflip_f32((unsigned int)(my >> 32));
            int o = b * NK + rank;
            idx_out[o] = idx;
            vals_out[o] = val;
            y_out[o] = (float)(idx / NW);
            x_out[o] = (float)(idx % NW);
        }
    }
}

// ---- kernel 4: gather point features [B,K,C] (R10-exact) --------------------
__global__ void __launch_bounds__(256)
gather_kernel(const float* __restrict__ f, const int* __restrict__ idx,
              float* __restrict__ out) {
    int bid = blockIdx.x;              // 1024
    int xcd = bid & 7, i = bid >> 3;   // i 0..127
    int b = xcd + 8 * (i & 1);
    int kg = i >> 1;                   // 0..63
    int c = threadIdx.x;
    const float* fb = f + (size_t)b * NC * NHW + (size_t)c * NHW;
#pragma unroll
    for (int j = 0; j < 4; ++j) {
        int k = kg * 4 + j;
        int p = idx[b * NK + k];       // uniform -> scalar load
        out[((size_t)b * NK + k) * NC + c] = fb[p];
    }
}

extern "C" void kernel_launch(void* const* d_in, const int* in_sizes, int n_in,
                              void* d_out, int out_size, void* d_ws, size_t ws_size,
                              hipStream_t stream) {
    const float* f = (const float*)d_in[0];

    // output layout: point_feat [B,K,C] | vals [B,K] | ycoord [B,K] | xcoord [B,K]
    float* out_feat = (float*)d_out;
    float* out_vals = out_feat + (size_t)NB * NK * NC;
    float* out_y    = out_vals + (size_t)NB * NK;
    float* out_x    = out_y    + (size_t)NB * NK;

    // workspace: 6 partial maps | svals map | idx
    float* maps = (float*)d_ws;
    unsigned int* sv = (unsigned int*)(maps + 6 * (size_t)MAPS);
    int* idx = (int*)(sv + MAPS);

    pass1_kernel<<<P1_BLOCKS, 256, 0, stream>>>(f, maps);
    sim_kernel<<<(NB * NHW + 255) / 256, 256, 0, stream>>>(maps, sv);
    topk_kernel<<<NB, 1024, 0, stream>>>(sv, idx, out_vals, out_y, out_x);
    gather_kernel<<<NB * NK / 4, 256, 0, stream>>>(f, idx, out_feat);
}

// Round 13
// 37.718 us; speedup vs baseline: 4.7699x; 1.0067x over previous
//
#include <hip/hip_runtime.h>

#define NB 16
#define NC 256
#define NH 56
#define NW 56
#define NHW (NH * NW)          // 3136
#define NK 256
#define CAP 1024

// pass1 geometry: 8-row band x quarter channels per block -> 448 blocks
#define BR 8                   // compute rows per band
#define RS 10                  // staged rows (8 compute + 2 halo)
#define CS 8                   // channels per staged chunk
#define CQ 64                  // channels per block (quarter)
#define NCHUNK (CQ / CS)       // 8 chunks per block
#define CHUNK16 (CS * RS * NW / 4)        // 1120 16B-chunks per stage
#define NBAND (NH / BR)                   // 7
#define P1_BLOCKS (NB * NBAND * 4)        // 448 (56 per XCD)
#define NQ (BR * (NW / 4))                // 112 quads per band
#define MAPS (NB * NHW)                   // elements per map

// ---- sortable-float helpers -------------------------------------------------
__device__ inline unsigned int flip_f32(float f) {
    unsigned int u = __float_as_uint(f);
    return (u & 0x80000000u) ? ~u : (u | 0x80000000u);
}
__device__ inline float unflip_f32(unsigned int u) {
    u = (u & 0x80000000u) ? (u ^ 0x80000000u) : ~u;
    return __uint_as_float(u);
}

// ---- kernel 1: partial norm2 / hprod / vprod maps ---------------------------
// Block = (batch, 8-row band, channel-quarter). 10 staged rows per 8 produced
// -> 1.25x amplification (64 MB vs R12's 77 MB) at the SAME 448-block grid.
// LDS 46.6 KB -> 3 blocks/CU. Four quarter-partials summed by sim_kernel in
// fixed order (deterministic).
__global__ void __launch_bounds__(256)
pass1_kernel(const float* __restrict__ f, float* __restrict__ maps) {
    __shared__ __align__(16) float buf[2][CS * RS * NW];   // 2 x 17920 B
    __shared__ float redbuf[NQ][2][12];                    // 10752 B

    int bid = blockIdx.x;
    int sb = (bid & 7) * (P1_BLOCKS / 8) + (bid >> 3);   // XCD-chunked
    int b = sb / 28;
    int rem0 = sb - b * 28;
    int band = rem0 >> 2;          // 0..6
    int chq = rem0 & 3;            // channel quarter
    int y0 = band * BR;
    int tid = threadIdx.x;
    const float* fb = f + (size_t)b * NC * NHW + (size_t)chq * CQ * NHW;

    auto stage = [&](int ci, float* dst) {
        int c0 = ci * CS;
#pragma unroll
        for (int i = 0; i < 5; ++i) {
            int k = tid + 256 * i;
            if (k < CHUNK16) {
                int ch = k / (RS * 14);            // 140 16B-chunks per channel
                int rem = k - ch * (RS * 14);
                int rl = rem / 14;                 // staged row 0..9
                int xk = rem - rl * 14;            // 16B chunk within row
                int rg = y0 - 1 + rl;
                rg = rg < 0 ? 0 : (rg > NH - 1 ? NH - 1 : rg);
                const float* src = fb + (size_t)(c0 + ch) * NHW + rg * NW + xk * 4;
                __builtin_amdgcn_global_load_lds(
                    (const __attribute__((address_space(1))) void*)src,
                    (__attribute__((address_space(3))) void*)(dst + k * 4),
                    16, 0, 0);
            }
        }
    };

    // compute geometry: tid<224 -> quad (8 rows x 14 quads) x chgroup(2)
    int chg = tid / NQ;                 // 0..1, each handles 4 ch per chunk
    int quad = tid - chg * NQ;          // 0..111
    int r = quad / 14, qx = quad - r * 14, x0 = qx * 4;
    int xl = x0 ? x0 - 1 : 0;
    int xr = (x0 + 4 < NW) ? x0 + 4 : NW - 1;

    float n0 = 0.f, n1 = 0.f, n2 = 0.f, n3 = 0.f;
    float h0 = 0.f, h1 = 0.f, h2 = 0.f, h3 = 0.f;
    float w0 = 0.f, w1 = 0.f, w2 = 0.f, w3 = 0.f;

    stage(0, buf[0]);
    __syncthreads();                            // drains staging
    for (int ci = 0; ci < NCHUNK; ++ci) {
        if (ci + 1 < NCHUNK) stage(ci + 1, buf[(ci + 1) & 1]);
        if (tid < 2 * NQ) {
            const float* sbf = buf[ci & 1];
#pragma unroll
            for (int c = 0; c < 4; ++c) {
                const float* Bm = sbf + (chg * 4 + c) * (RS * NW) + (r + 1) * NW;
                float4 v = *(const float4*)(Bm + x0);
                float  l = Bm[xl];
                float  rr = Bm[xr];
                float4 u = *(const float4*)(Bm + NW + x0);   // global y+1
                float4 d = *(const float4*)(Bm - NW + x0);   // global y-1
                n0 += v.x * v.x; n1 += v.y * v.y; n2 += v.z * v.z; n3 += v.w * v.w;
                h0 += l * v.y;   h1 += v.x * v.z; h2 += v.y * v.w; h3 += v.z * rr;
                w0 += u.x * d.x; w1 += u.y * d.y; w2 += u.z * d.z; w3 += u.w * d.w;
            }
        }
        __syncthreads();   // compute done + next stage landed
    }

    if (tid < 2 * NQ) {
        float* rb = redbuf[quad][chg];
        rb[0] = n0; rb[1] = n1; rb[2]  = n2; rb[3]  = n3;
        rb[4] = h0; rb[5] = h1; rb[6]  = h2; rb[7]  = h3;
        rb[8] = w0; rb[9] = w1; rb[10] = w2; rb[11] = w3;
    }
    __syncthreads();

    // maps layout: [chq][class n/h/v][B*HW]
    float* mbase = maps + (size_t)chq * 3 * MAPS;
    for (int oi = tid; oi < NQ * 12; oi += 256) {
        int q = oi / 12, comp = oi - q * 12;
        float acc = redbuf[q][0][comp] + redbuf[q][1][comp];
        int r2 = q / 14, qx2 = q - r2 * 14;
        int j = comp & 3;
        float* m = mbase + (size_t)(comp >> 2) * MAPS;   // 0:n 1:h 2:v
        m[((size_t)b * NH + y0 + r2) * NW + qx2 * 4 + j] = acc;
    }
}

// ---- kernel 2: sim-finish ---------------------------------------------------
// Sums 4 channel-quarter partials in fixed ascending order.
__global__ void __launch_bounds__(256)
sim_kernel(const float* __restrict__ maps, unsigned int* __restrict__ sv) {
    int pix = blockIdx.x * 256 + threadIdx.x;
    if (pix >= NB * NHW) return;
    int b = pix / NHW, i = pix - b * NHW;

    int y = i / NW, x = i - y * NW;
    int xl = (x > 0) ? x - 1 : 0;
    int xr = (x < NW - 1) ? x + 1 : NW - 1;
    int yu = (y < NH - 1) ? y + 1 : NH - 1;
    int yd = (y > 0) ? y - 1 : 0;
    int il = y * NW + xl, ir = y * NW + xr;
    int iu = yu * NW + x, id = yd * NW + x;

    float nl = 0.f, nr = 0.f, nu = 0.f, nd = 0.f, h = 0.f, v = 0.f;
#pragma unroll
    for (int q = 0; q < 4; ++q) {
        const float* nq = maps + (size_t)(q * 3 + 0) * MAPS + (size_t)b * NHW;
        const float* hq = maps + (size_t)(q * 3 + 1) * MAPS + (size_t)b * NHW;
        const float* vq = maps + (size_t)(q * 3 + 2) * MAPS + (size_t)b * NHW;
        nl += nq[il]; nr += nq[ir]; nu += nq[iu]; nd += nq[id];
        h  += hq[i];  v  += vq[i];
    }
    float s = 0.5f * (h / (sqrtf(nl) * sqrtf(nr)) + v / (sqrtf(nu) * sqrtf(nd)));
    sv[pix] = flip_f32(s);
}

// ---- kernel 3: per-batch top-K (R12-exact) ----------------------------------
__global__ void __launch_bounds__(1024)
topk_kernel(const unsigned int* __restrict__ sv, int* __restrict__ idx_out,
            float* __restrict__ vals_out, float* __restrict__ y_out,
            float* __restrict__ x_out) {
    __shared__ unsigned int svals[NHW];
    __shared__ unsigned int hist[4096];
    __shared__ unsigned int wtot[16];
    __shared__ unsigned long long cand[CAP];
    __shared__ unsigned int sh_prefix, sh_mask;
    __shared__ int sh_above, sh_setS, sh_done, sh_cnt;

    const int b = blockIdx.x;
    const int tid = threadIdx.x;
    const int lane = tid & 63;
    const int wv = tid >> 6;
    const unsigned int* svb = sv + (size_t)b * NHW;

    for (int i = tid; i < NHW; i += 1024) svals[i] = svb[i];
    if (tid == 0) { sh_prefix = 0u; sh_mask = 0u; sh_above = 0; sh_done = 0; }

    const int shifts[3] = {20, 8, 0};
    const unsigned int wmasks[3] = {0xFFFu, 0xFFFu, 0xFFu};
    for (int st = 0; st < 3; ++st) {
        __syncthreads();
        int kneed = NK - sh_above;          // read post-barrier, pre-update
        if (sh_done) break;
        for (int i = tid; i < 4096; i += 1024) hist[i] = 0u;
        __syncthreads();
        unsigned int pfx = sh_prefix, msk = sh_mask;
        int shift = shifts[st];
        unsigned int wmask = wmasks[st];
        for (int i = tid; i < NHW; i += 1024) {
            unsigned int v = svals[i];
            if ((v & msk) == pfx) atomicAdd(&hist[(v >> shift) & wmask], 1u);
        }
        __syncthreads();
        // block-wide suffix scan: thread t owns bins 4t..4t+3 (ascending value)
        unsigned int b0 = hist[4 * tid], b1 = hist[4 * tid + 1];
        unsigned int b2 = hist[4 * tid + 2], b3 = hist[4 * tid + 3];
        unsigned int lsum = b0 + b1 + b2 + b3;
        unsigned int s = lsum;
#pragma unroll
        for (int d = 1; d < 64; d <<= 1) {
            unsigned int t2 = __shfl_down(s, d);
            s += (lane + d < 64) ? t2 : 0u;
        }
        if (lane == 0) wtot[wv] = s;        // wave total
        __syncthreads();
        unsigned int wabove = 0;
        for (int w = wv + 1; w < 16; ++w) wabove += wtot[w];
        unsigned int thr_above = wabove + (s - lsum);   // strictly above my bins
        unsigned int suf3 = thr_above + b3;
        unsigned int suf2 = suf3 + b2;
        unsigned int suf1 = suf2 + b1;
        unsigned int suf0 = suf1 + b0;
        // unique boundary thread self-identifies
        if (suf0 >= (unsigned int)kneed && thr_above < (unsigned int)kneed) {
            int c; unsigned int above, hc;
            if (suf3 >= (unsigned int)kneed)      { c = 4 * tid + 3; above = thr_above; hc = b3; }
            else if (suf2 >= (unsigned int)kneed) { c = 4 * tid + 2; above = suf3;      hc = b2; }
            else if (suf1 >= (unsigned int)kneed) { c = 4 * tid + 1; above = suf2;      hc = b1; }
            else                                  { c = 4 * tid + 0; above = suf1;      hc = b0; }
            sh_above += (int)above;
            sh_setS = (int)hc;
            sh_prefix = pfx | ((unsigned int)c << shift);
            sh_mask = msk | (wmask << shift);
            if (sh_above + sh_setS <= CAP || st == 2) sh_done = 1;
        }
    }
    __syncthreads();

    // ballot-aggregated compaction of candidates v >= T
    if (tid == 0) sh_cnt = 0;
    __syncthreads();
    unsigned int T = sh_prefix;
    for (int i = tid; i < NHW; i += 1024) {
        unsigned int v = svals[i];
        bool keep = (v >= T);
        unsigned long long m = __ballot(keep);
        int basep = 0;
        if (lane == 0) basep = atomicAdd(&sh_cnt, __popcll(m));
        basep = __shfl(basep, 0);
        if (keep) {
            int pos = basep + __popcll(m & ((1ull << lane) - 1ull));
            if (pos < CAP)
                cand[pos] = ((unsigned long long)v << 32) |
                            (unsigned long long)(0xFFFFFFFFu - (unsigned int)i);
        }
    }
    __syncthreads();
    int nc = sh_cnt; if (nc > CAP) nc = CAP;

    // counting-rank: thread t ranks its candidate against all nc (LDS
    // broadcast reads), writes straight to out[rank].
    if (tid < nc) {
        unsigned long long my = cand[tid];
        int rank = 0;
        for (int i = 0; i < nc; ++i) rank += (cand[i] > my);
        if (rank < NK) {
            unsigned int lo = (unsigned int)(my & 0xFFFFFFFFull);
            int idx = (int)(0xFFFFFFFFu - lo);
            float val = unflip_f32((unsigned int)(my >> 32));
            int o = b * NK + rank;
            idx_out[o] = idx;
            vals_out[o] = val;
            y_out[o] = (float)(idx / NW);
            x_out[o] = (float)(idx % NW);
        }
    }
}

// ---- kernel 4: gather point features [B,K,C] --------------------------------
// Block = (batch, 8-channel tile) owns ALL 256 points: each (b,c) 64B line is
// fetched exactly ONCE chip-wide and reused from L1 (12.5 KB image << 32 KB
// L1). Thread t holds v[0..7] = out[k=t][c0..c0+7] -> two direct float4
// stores, no LDS. Fixes the MSHR-latency wall of the thread=channel layout
// (1M once-per-lane line fetches -> ~586K once-only fetches + L1 hits).
#define GCT 8
__global__ void __launch_bounds__(256)
gather_kernel(const float* __restrict__ f, const int* __restrict__ idx,
              float* __restrict__ out) {
    int bid = blockIdx.x;              // 512 = 16 b x 32 ctiles
    int b = bid >> 5;
    int c0 = (bid & 31) * GCT;
    int t = threadIdx.x;               // point rank k
    int p = idx[b * NK + t];
    const float* fb = f + (size_t)b * NC * NHW + (size_t)c0 * NHW;

    float v[GCT];
#pragma unroll
    for (int ci = 0; ci < GCT; ++ci) v[ci] = fb[(size_t)ci * NHW + p];

    float4 a = make_float4(v[0], v[1], v[2], v[3]);
    float4 b4 = make_float4(v[4], v[5], v[6], v[7]);
    float* op = out + ((size_t)b * NK + t) * NC + c0;
    *(float4*)op = a;
    *(float4*)(op + 4) = b4;
}

extern "C" void kernel_launch(void* const* d_in, const int* in_sizes, int n_in,
                              void* d_out, int out_size, void* d_ws, size_t ws_size,
                              hipStream_t stream) {
    const float* f = (const float*)d_in[0];

    // output layout: point_feat [B,K,C] | vals [B,K] | ycoord [B,K] | xcoord [B,K]
    float* out_feat = (float*)d_out;
    float* out_vals = out_feat + (size_t)NB * NK * NC;
    float* out_y    = out_vals + (size_t)NB * NK;
    float* out_x    = out_y    + (size_t)NB * NK;

    // workspace: 12 partial maps (n,h,v x 4 quarters) | svals map | idx
    float* maps = (float*)d_ws;
    unsigned int* sv = (unsigned int*)(maps + 12 * (size_t)MAPS);
    int* idx = (int*)(sv + MAPS);

    pass1_kernel<<<P1_BLOCKS, 256, 0, stream>>>(f, maps);
    sim_kernel<<<(NB * NHW + 255) / 256, 256, 0, stream>>>(maps, sv);
    topk_kernel<<<NB, 1024, 0, stream>>>(sv, idx, out_vals, out_y, out_x);
    gather_kernel<<<NB * (NC / GCT), 256, 0, stream>>>(f, idx, out_feat);
}